// Round 13
// baseline (406.865 us; speedup 1.0000x reference)
//
#include <hip/hip_runtime.h>
#include <hip/hip_bf16.h>
#include <cstdint>
#include <cstddef>

typedef __bf16 bf16x8 __attribute__((ext_vector_type(8)));
typedef __bf16 bf16x4 __attribute__((ext_vector_type(4)));
typedef float  f32x4  __attribute__((ext_vector_type(4)));

__device__ __forceinline__ void lds_load16(const void* gsrc, void* ldst) {
    __builtin_amdgcn_global_load_lds(
        (const __attribute__((address_space(1))) unsigned int*)gsrc,
        (__attribute__((address_space(3))) unsigned int*)ldst,
        16, 0, 0);
}

// ---------------- elementwise fp32 -> bf16 convert (x) ----------------
__global__ __launch_bounds__(256) void cvt_k(const float* __restrict__ in,
                                             __bf16* __restrict__ out, int n8) {
    int i = blockIdx.x * 256 + threadIdx.x;
    if (i >= n8) return;
    const float4* p4 = (const float4*)in + (size_t)i * 2;
    float4 a = p4[0], b = p4[1];
    bf16x8 o;
    o[0] = (__bf16)a.x; o[1] = (__bf16)a.y; o[2] = (__bf16)a.z; o[3] = (__bf16)a.w;
    o[4] = (__bf16)b.x; o[5] = (__bf16)b.y; o[6] = (__bf16)b.z; o[7] = (__bf16)b.w;
    *((bf16x8*)out + i) = o;
}

// ---------------- transpose fp32 [R][C] -> bf16 [C][R] ----------------
__global__ __launch_bounds__(256) void transp_k(const float* __restrict__ W,
                                                __bf16* __restrict__ WT, int R, int C) {
    __shared__ float tile[32][33];
    int tx = threadIdx.x & 31, ty = threadIdx.x >> 5;
    int c0 = blockIdx.x * 32, r0 = blockIdx.y * 32;
#pragma unroll
    for (int k = 0; k < 4; ++k)
        tile[ty + 8 * k][tx] = W[(size_t)(r0 + ty + 8 * k) * C + c0 + tx];
    __syncthreads();
#pragma unroll
    for (int k = 0; k < 4; ++k)
        WT[(size_t)(c0 + ty + 8 * k) * R + r0 + tx] = (__bf16)tile[tx][ty + 8 * k];
}

// ---------------- cos/sin table [2048][64] (float2 = cos,sin) ----------------
__global__ __launch_bounds__(256) void sincos_k(float2* __restrict__ sc) {
    int idx = blockIdx.x * 256 + threadIdx.x;  // 131072
    int t = idx >> 6, j = idx & 63;
    float inv = powf(10000.f, -(float)j / 64.f);
    float f = (float)t * inv;
    float s, c;
    sincosf(f, &s, &c);
    sc[idx] = make_float2(c, s);
}

// ---------------- 256x256x64 bf16 GEMM, m201-style 4-phase schedule (best measured) ----
__global__ __launch_bounds__(512, 2) void gemm8_k(const __bf16* __restrict__ A,
                                                  const __bf16* __restrict__ Bt,
                                                  int nbn, int mode,
                                                  __bf16* __restrict__ qb, __bf16* __restrict__ kb,
                                                  __bf16* __restrict__ vt,
                                                  float* __restrict__ outp,
                                                  const float* __restrict__ bias,
                                                  const float2* __restrict__ sc) {
    __shared__ __bf16 lds[2][2][2][128 * 64];  // [dbuf][A=0/B=1][sub][r*64+c]  128 KiB
    const int K = 2048, NT = K / 64;
    int nwg = gridDim.x;
    int per = nwg >> 3;
    int bid = blockIdx.x;
    int wg = (bid & 7) * per + (bid >> 3);  // XCD swizzle (nwg % 8 == 0)
    int bm = wg / nbn, bn = wg % nbn;
    int m0 = bm * 256, n0 = bn * 256;
    int tid = threadIdx.x;
    int lane = tid & 63, wave = tid >> 6;
    int wm = wave >> 2, wn = wave & 3;
    int lr = lane & 15, lg = lane >> 4;

    f32x4 acc[8][4] = {};

    auto stageA = [&](int db, int sub, int kt) {
#pragma unroll
        for (int l = 0; l < 2; ++l) {
            int chunk = l * 512 + tid;
            int r = chunk >> 3, c16 = chunk & 7;
            int rg = m0 + ((r >> 6) << 7) + (sub << 6) + (r & 63);
            lds_load16(A + (size_t)rg * K + (kt << 6) + ((c16 ^ (r & 7)) << 3),
                       &lds[db][0][sub][chunk * 8]);
        }
    };
    auto stageB = [&](int db, int sub, int kt) {
#pragma unroll
        for (int l = 0; l < 2; ++l) {
            int chunk = l * 512 + tid;
            int r = chunk >> 3, c16 = chunk & 7;
            int rg = n0 + ((r >> 5) << 6) + (sub << 5) + (r & 31);
            lds_load16(Bt + (size_t)rg * K + (kt << 6) + ((c16 ^ (r & 7)) << 3),
                       &lds[db][1][sub][chunk * 8]);
        }
    };
    auto rdA = [&](int db, int sub, int q, int kk) -> bf16x8 {
        int r = (wm << 6) + (q << 4) + lr;
        int cb = ((kk << 6) + (lg << 4)) ^ ((r & 7) << 4);
        return *(const bf16x8*)((const char*)&lds[db][0][sub][0] + r * 128 + cb);
    };
    auto rdB = [&](int db, int j, int kk) -> bf16x8 {
        int sub = j >> 1;
        int r = (wn << 5) + ((j & 1) << 4) + lr;
        int cb = ((kk << 6) + (lg << 4)) ^ ((r & 7) << 4);
        return *(const bf16x8*)((const char*)&lds[db][1][sub][0] + r * 128 + cb);
    };

    stageA(0, 0, 0); stageB(0, 0, 0); stageB(0, 1, 0); stageA(0, 1, 0);
    asm volatile("s_waitcnt vmcnt(4)" ::: "memory");
    __builtin_amdgcn_s_barrier();

    bf16x8 a[4][2], bA[2][2], bB[2][2];
    for (int t = 0; t < NT; ++t) {
        int db = t & 1, dn = db ^ 1;
        bool pf = (t + 1 < NT);
        // ---------- phase 0 ----------
#pragma unroll
        for (int q = 0; q < 4; ++q) { a[q][0] = rdA(db, 0, q, 0); a[q][1] = rdA(db, 0, q, 1); }
#pragma unroll
        for (int j = 0; j < 2; ++j) { bA[j][0] = rdB(db, j, 0); bA[j][1] = rdB(db, j, 1); }
        if (pf) stageA(dn, 0, t + 1);
        __builtin_amdgcn_s_barrier();
        asm volatile("s_waitcnt lgkmcnt(0)" ::: "memory");
        __builtin_amdgcn_sched_barrier(0);
        __builtin_amdgcn_s_setprio(1);
#pragma unroll
        for (int q = 0; q < 4; ++q)
#pragma unroll
            for (int j = 0; j < 2; ++j)
#pragma unroll
                for (int kk = 0; kk < 2; ++kk)
                    acc[q][j] = __builtin_amdgcn_mfma_f32_16x16x32_bf16(a[q][kk], bA[j][kk], acc[q][j], 0, 0, 0);
        __builtin_amdgcn_s_setprio(0);
        if (pf) asm volatile("s_waitcnt vmcnt(4)" ::: "memory");
        else    asm volatile("s_waitcnt vmcnt(2)" ::: "memory");
        __builtin_amdgcn_s_barrier();
        // ---------- phase 1 ----------
#pragma unroll
        for (int j = 0; j < 2; ++j) { bB[j][0] = rdB(db, j + 2, 0); bB[j][1] = rdB(db, j + 2, 1); }
        if (pf) stageB(dn, 0, t + 1);
        __builtin_amdgcn_s_barrier();
        asm volatile("s_waitcnt lgkmcnt(0)" ::: "memory");
        __builtin_amdgcn_sched_barrier(0);
        __builtin_amdgcn_s_setprio(1);
#pragma unroll
        for (int q = 0; q < 4; ++q)
#pragma unroll
            for (int j = 0; j < 2; ++j)
#pragma unroll
                for (int kk = 0; kk < 2; ++kk)
                    acc[q][j + 2] = __builtin_amdgcn_mfma_f32_16x16x32_bf16(a[q][kk], bB[j][kk], acc[q][j + 2], 0, 0, 0);
        __builtin_amdgcn_s_setprio(0);
        if (pf) asm volatile("s_waitcnt vmcnt(4)" ::: "memory");
        else    asm volatile("s_waitcnt vmcnt(0)" ::: "memory");
        __builtin_amdgcn_s_barrier();
        // ---------- phase 2 ----------
#pragma unroll
        for (int q = 0; q < 4; ++q) { a[q][0] = rdA(db, 1, q, 0); a[q][1] = rdA(db, 1, q, 1); }
        if (pf) stageB(dn, 1, t + 1);
        __builtin_amdgcn_s_barrier();
        asm volatile("s_waitcnt lgkmcnt(0)" ::: "memory");
        __builtin_amdgcn_sched_barrier(0);
        __builtin_amdgcn_s_setprio(1);
#pragma unroll
        for (int q = 0; q < 4; ++q)
#pragma unroll
            for (int j = 0; j < 2; ++j)
#pragma unroll
                for (int kk = 0; kk < 2; ++kk)
                    acc[q + 4][j + 2] = __builtin_amdgcn_mfma_f32_16x16x32_bf16(a[q][kk], bB[j][kk], acc[q + 4][j + 2], 0, 0, 0);
        __builtin_amdgcn_s_setprio(0);
        __builtin_amdgcn_s_barrier();
        // ---------- phase 3 ----------
        if (pf) stageA(dn, 1, t + 1);
        __builtin_amdgcn_s_setprio(1);
#pragma unroll
        for (int q = 0; q < 4; ++q)
#pragma unroll
            for (int j = 0; j < 2; ++j)
#pragma unroll
                for (int kk = 0; kk < 2; ++kk)
                    acc[q + 4][j] = __builtin_amdgcn_mfma_f32_16x16x32_bf16(a[q][kk], bA[j][kk], acc[q + 4][j], 0, 0, 0);
        __builtin_amdgcn_s_setprio(0);
        if (pf) asm volatile("s_waitcnt vmcnt(4)" ::: "memory");
        __builtin_amdgcn_s_barrier();
    }

    // -------- epilogue --------
    if (mode == 0) {
        int which = n0 >> 11;  // 0:q 1:k 2:v (block-uniform)
        if (which == 2) {
#pragma unroll
            for (int q = 0; q < 8; ++q) {
                int row_t = (wm << 7) + ((q >> 2) << 6) + ((q & 3) << 4) + (lg << 2);
                int row = m0 + row_t;
                int b_ = row >> 11, tt = row & 2047;   // r=0..3 stays within batch (4-aligned)
#pragma unroll
                for (int j = 0; j < 4; ++j) {
                    int c = n0 + (wn << 6) + (j << 4) + lr;
                    int h = (c & 2047) >> 7, d = c & 127;
                    bf16x4 o;
#pragma unroll
                    for (int r = 0; r < 4; ++r) o[r] = (__bf16)acc[q][j][r];
                    *(bf16x4*)(vt + ((size_t)(b_ * 16 + h) * 128 + d) * 2048 + tt) = o;
                }
            }
        } else {
            // fused RoPE (fp32): exchange the d<->d^64 partner through LDS scratch
            __bf16* dst = (which == 0) ? qb : kb;
            float scale = (which == 0) ? 0.08838834764831845f : 1.f;  // 1/sqrt(128) on q
            int rl = (wm << 4) + (lg << 2);
            int colw = (wn << 6);
#pragma unroll
            for (int q = 0; q < 8; ++q) {
                float* scr = (float*)&lds[q & 1][0][0][0];  // alternate 64KiB halves
                int row_t = (wm << 7) + ((q >> 2) << 6) + ((q & 3) << 4) + (lg << 2);
#pragma unroll
                for (int j = 0; j < 4; ++j)
#pragma unroll
                    for (int r = 0; r < 4; ++r)
                        scr[(rl + r) * 260 + colw + (j << 4) + lr] = acc[q][j][r];
                __syncthreads();
#pragma unroll
                for (int j = 0; j < 4; ++j) {
                    int c = n0 + colw + (j << 4) + lr;
                    int h = (c & 2047) >> 7, d = c & 127;
                    int jj = (j << 4) + lr;  // d % 64
#pragma unroll
                    for (int r = 0; r < 4; ++r) {
                        int row = m0 + row_t + r;
                        int b_ = row >> 11, tt = row & 2047;
                        float2 cs = sc[tt * 64 + jj];
                        float v0 = acc[q][j][r];
                        float v1 = scr[(rl + r) * 260 + (colw ^ 64) + (j << 4) + lr];
                        float o = ((wn & 1) == 0) ? (v0 * cs.x - v1 * cs.y)
                                                  : (v0 * cs.x + v1 * cs.y);
                        dst[((size_t)(b_ * 16 + h) * 2048 + tt) * 128 + d] = (__bf16)(o * scale);
                    }
                }
            }
        }
    } else {
#pragma unroll
        for (int q = 0; q < 8; ++q) {
            int row_t = (wm << 7) + ((q >> 2) << 6) + ((q & 3) << 4) + (lg << 2);
#pragma unroll
            for (int j = 0; j < 4; ++j) {
                int col = n0 + (wn << 6) + (j << 4) + lr;
                float bv = bias[col];
#pragma unroll
                for (int r = 0; r < 4; ++r) {
                    int row = m0 + row_t + r;
                    outp[(size_t)row * 2048 + col] = acc[q][j][r] + bv;
                }
            }
        }
    }
}

// ---------------- causal flash attention, QBLK=128, 8 waves (R8 + max3-tree fmax) ------
__global__ __launch_bounds__(512, 2) void attn_k(const __bf16* __restrict__ qb,
                                                 const __bf16* __restrict__ kb,
                                                 const __bf16* __restrict__ vt,
                                                 __bf16* __restrict__ ao) {
    __shared__ __bf16 Ks[64 * 128];   // [kv][d], rows 256B, XOR-swizzled
    __shared__ __bf16 Vs[128 * 64];   // [d][kv], rows 128B, XOR-swizzled
    __shared__ __bf16 Ps[8][16 * 64]; // per-wave P^T as [q][kv], rows 128B, swizzled

    int bid = blockIdx.x;
    int qt = 15 - (bid >> 6);
    int bh = bid & 63;
    int qs = qt * 128;
    int tid = threadIdx.x, wave = tid >> 6, lane = tid & 63;
    int lr = lane & 15, lg = lane >> 4;

    bf16x8 qf[4];
    const __bf16* Qrow = qb + ((size_t)bh * 2048 + qs + wave * 16 + lr) * 128;
#pragma unroll
    for (int kk = 0; kk < 4; ++kk) qf[kk] = *(const bf16x8*)(Qrow + kk * 32 + lg * 8);

    f32x4 ot[8] = {};
    float m_run = -1e30f, l_run = 0.f;
    int qmax = qs + wave * 16 + 15;
    int kend = qs + 64;

    for (int ks = 0; ks <= kend; ks += 64) {
#pragma unroll
        for (int i = 0; i < 2; ++i) {
            int c = tid + i * 512;
            {
                int row = c >> 4;
                int cc = c ^ (row & 7);
                int dd = (cc & 15) * 8;
                lds_load16(kb + ((size_t)bh * 2048 + ks + row) * 128 + dd, Ks + c * 8);
            }
            {
                int row = c >> 3;
                int cc = c ^ (row & 7);
                int tt = (cc & 7) * 8;
                lds_load16(vt + ((size_t)bh * 128 + row) * 2048 + ks + tt, Vs + c * 8);
            }
        }
        __syncthreads();

        if (ks <= qmax) {
            f32x4 st[4];
            __builtin_amdgcn_s_setprio(1);
#pragma unroll
            for (int mt = 0; mt < 4; ++mt) {
                f32x4 s = {};
#pragma unroll
                for (int kk = 0; kk < 4; ++kk) {
                    int row = mt * 16 + lr;
                    const __bf16* kp = Ks + row * 128 + ((((kk * 64 + lg * 16)) ^ ((row & 7) << 4)) >> 1);
                    bf16x8 afr = *(const bf16x8*)kp;
                    s = __builtin_amdgcn_mfma_f32_16x16x32_bf16(afr, qf[kk], s, 0, 0, 0);
                }
                st[mt] = s;
            }
            __builtin_amdgcn_s_setprio(0);

            if (ks + 63 > qs + wave * 16) {
                int q = qs + wave * 16 + lr;
#pragma unroll
                for (int mt = 0; mt < 4; ++mt)
#pragma unroll
                    for (int r = 0; r < 4; ++r) {
                        int kv = ks + mt * 16 + lg * 4 + r;
                        if (kv > q) st[mt][r] = -1e30f;
                    }
            }

            // tile row-max: nested trees so clang can fuse v_max3 (T17)
            float pmt[4];
#pragma unroll
            for (int mt = 0; mt < 4; ++mt)
                pmt[mt] = fmaxf(fmaxf(st[mt][0], st[mt][1]), fmaxf(st[mt][2], st[mt][3]));
            float pm = fmaxf(fmaxf(pmt[0], pmt[1]), fmaxf(pmt[2], pmt[3]));
            pm = fmaxf(pm, __shfl_xor(pm, 16));
            pm = fmaxf(pm, __shfl_xor(pm, 32));
            float nm = fmaxf(m_run, pm);
            float alpha = __expf(m_run - nm);
            float psum = 0.f;
#pragma unroll
            for (int mt = 0; mt < 4; ++mt)
#pragma unroll
                for (int r = 0; r < 4; ++r) {
                    float p = __expf(st[mt][r] - nm);
                    psum += p;
                    st[mt][r] = p;
                }
            psum += __shfl_xor(psum, 16);
            psum += __shfl_xor(psum, 32);
            l_run = l_run * alpha + psum;
            m_run = nm;
#pragma unroll
            for (int t8 = 0; t8 < 8; ++t8) ot[t8] *= alpha;

#pragma unroll
            for (int mt = 0; mt < 4; ++mt) {
                bf16x4 pk;
#pragma unroll
                for (int r = 0; r < 4; ++r) pk[r] = (__bf16)st[mt][r];
                int byteoff = lr * 128 + (((mt * 32 + lg * 8)) ^ ((lr & 7) << 4));
                *(bf16x4*)((char*)&Ps[wave][0] + byteoff) = pk;
            }

            bf16x8 pfr[2];
#pragma unroll
            for (int kk = 0; kk < 2; ++kk) {
                const char* pp = (const char*)&Ps[wave][0] + lr * 128 + (((kk * 64 + lg * 16)) ^ ((lr & 7) << 4));
                pfr[kk] = *(const bf16x8*)pp;
            }
            __builtin_amdgcn_s_setprio(1);
#pragma unroll
            for (int dt = 0; dt < 8; ++dt) {
#pragma unroll
                for (int kk = 0; kk < 2; ++kk) {
                    int row = dt * 16 + lr;
                    const __bf16* vp = Vs + row * 64 + ((((kk * 64 + lg * 16)) ^ ((row & 7) << 4)) >> 1);
                    bf16x8 afr = *(const bf16x8*)vp;
                    ot[dt] = __builtin_amdgcn_mfma_f32_16x16x32_bf16(afr, pfr[kk], ot[dt], 0, 0, 0);
                }
            }
            __builtin_amdgcn_s_setprio(0);
        }
        __syncthreads();
    }

    float inv = 1.f / l_run;
    int b_ = bh >> 4, h = bh & 15;
    size_t rowbase = ((size_t)b_ * 2048 + qs + wave * 16 + lr) * 2048 + h * 128;
#pragma unroll
    for (int dt = 0; dt < 8; ++dt) {
        bf16x4 o;
#pragma unroll
        for (int r = 0; r < 4; ++r) o[r] = (__bf16)(ot[dt][r] * inv);
        *(bf16x4*)(ao + rowbase + dt * 16 + lg * 4) = o;
    }
}

// ---------------- launch ----------------
extern "C" void kernel_launch(void* const* d_in, const int* in_sizes, int n_in,
                              void* d_out, int out_size, void* d_ws, size_t ws_size,
                              hipStream_t stream) {
    const float* x      = (const float*)d_in[0];
    const float* w_qkv  = (const float*)d_in[1];
    const float* w_proj = (const float*)d_in[2];
    const float* b_proj = (const float*)d_in[3];
    float* out = (float*)d_out;
    char* ws = (char*)d_ws;

    __bf16* xb  = (__bf16*)(ws);                 // [8192][2048]        33.55 MB
    __bf16* wqt = (__bf16*)(ws + 33554432);      // [6144][2048]        25.17 MB
    __bf16* wpt = (__bf16*)(ws + 58720256);      // [2048][2048]         8.39 MB
    __bf16* qb  = (__bf16*)(ws + 67108864);      // [64][2048][128]     33.55 MB
    __bf16* kb  = (__bf16*)(ws + 100663296);     // [64][2048][128]     33.55 MB
    __bf16* vt  = (__bf16*)(ws + 134217728);     // [64][128][2048]     33.55 MB
    __bf16* ao  = (__bf16*)(ws + 167772160);     // [8192][2048]        33.55 MB
    float2* sc  = (float2*)(ws + 201326592);     // [2048][64]           1.05 MB

    hipLaunchKernelGGL(cvt_k, dim3(8192), dim3(256), 0, stream, x, xb, 2097152);
    hipLaunchKernelGGL(transp_k, dim3(192, 64), dim3(256), 0, stream, w_qkv, wqt, 2048, 6144);
    hipLaunchKernelGGL(transp_k, dim3(64, 64), dim3(256), 0, stream, w_proj, wpt, 2048, 2048);
    hipLaunchKernelGGL(sincos_k, dim3(512), dim3(256), 0, stream, sc);
    // qkv: M=8192, N=6144 -> 32x24 = 768 tiles; RoPE fused in epilogue
    hipLaunchKernelGGL(gemm8_k, dim3(768), dim3(512), 0, stream,
                       xb, wqt, 24, 0, qb, kb, vt, (float*)nullptr, (const float*)nullptr, sc);
    hipLaunchKernelGGL(attn_k, dim3(1024), dim3(512), 0, stream, qb, kb, vt, ao);
    // proj: M=8192, N=2048 -> 32x8 = 256 tiles
    hipLaunchKernelGGL(gemm8_k, dim3(256), dim3(512), 0, stream,
                       ao, wpt, 8, 1, (__bf16*)nullptr, (__bf16*)nullptr, (__bf16*)nullptr,
                       out, b_proj, (const float2*)nullptr);
}

// Round 14
// 392.911 us; speedup vs baseline: 1.0355x; 1.0355x over previous
//
#include <hip/hip_runtime.h>
#include <hip/hip_bf16.h>
#include <cstdint>
#include <cstddef>

typedef __bf16 bf16x8 __attribute__((ext_vector_type(8)));
typedef __bf16 bf16x4 __attribute__((ext_vector_type(4)));
typedef float  f32x4  __attribute__((ext_vector_type(4)));

__device__ __forceinline__ void lds_load16(const void* gsrc, void* ldst) {
    __builtin_amdgcn_global_load_lds(
        (const __attribute__((address_space(1))) unsigned int*)gsrc,
        (__attribute__((address_space(3))) unsigned int*)ldst,
        16, 0, 0);
}

// ---------------- elementwise fp32 -> bf16 convert (x) ----------------
__global__ __launch_bounds__(256) void cvt_k(const float* __restrict__ in,
                                             __bf16* __restrict__ out, int n8) {
    int i = blockIdx.x * 256 + threadIdx.x;
    if (i >= n8) return;
    const float4* p4 = (const float4*)in + (size_t)i * 2;
    float4 a = p4[0], b = p4[1];
    bf16x8 o;
    o[0] = (__bf16)a.x; o[1] = (__bf16)a.y; o[2] = (__bf16)a.z; o[3] = (__bf16)a.w;
    o[4] = (__bf16)b.x; o[5] = (__bf16)b.y; o[6] = (__bf16)b.z; o[7] = (__bf16)b.w;
    *((bf16x8*)out + i) = o;
}

// ---------------- transpose fp32 [R][C] -> bf16 [C][R] ----------------
__global__ __launch_bounds__(256) void transp_k(const float* __restrict__ W,
                                                __bf16* __restrict__ WT, int R, int C) {
    __shared__ float tile[32][33];
    int tx = threadIdx.x & 31, ty = threadIdx.x >> 5;
    int c0 = blockIdx.x * 32, r0 = blockIdx.y * 32;
#pragma unroll
    for (int k = 0; k < 4; ++k)
        tile[ty + 8 * k][tx] = W[(size_t)(r0 + ty + 8 * k) * C + c0 + tx];
    __syncthreads();
#pragma unroll
    for (int k = 0; k < 4; ++k)
        WT[(size_t)(c0 + ty + 8 * k) * R + r0 + tx] = (__bf16)tile[tx][ty + 8 * k];
}

// ---------------- cos/sin table [2048][64] (float2 = cos,sin) ----------------
__global__ __launch_bounds__(256) void sincos_k(float2* __restrict__ sc) {
    int idx = blockIdx.x * 256 + threadIdx.x;  // 131072
    int t = idx >> 6, j = idx & 63;
    float inv = powf(10000.f, -(float)j / 64.f);
    float f = (float)t * inv;
    float s, c;
    sincosf(f, &s, &c);
    sc[idx] = make_float2(c, s);
}

// ---------------- 256x256x64 bf16 GEMM, m201-style 4-phase schedule (best measured) ----
__global__ __launch_bounds__(512, 2) void gemm8_k(const __bf16* __restrict__ A,
                                                  const __bf16* __restrict__ Bt,
                                                  int nbn, int mode,
                                                  __bf16* __restrict__ qb, __bf16* __restrict__ kb,
                                                  __bf16* __restrict__ vt,
                                                  float* __restrict__ outp,
                                                  const float* __restrict__ bias,
                                                  const float2* __restrict__ sc) {
    __shared__ __bf16 lds[2][2][2][128 * 64];  // [dbuf][A=0/B=1][sub][r*64+c]  128 KiB
    const int K = 2048, NT = K / 64;
    int nwg = gridDim.x;
    int per = nwg >> 3;
    int bid = blockIdx.x;
    int wg = (bid & 7) * per + (bid >> 3);  // XCD swizzle (nwg % 8 == 0)
    int bm = wg / nbn, bn = wg % nbn;
    int m0 = bm * 256, n0 = bn * 256;
    int tid = threadIdx.x;
    int lane = tid & 63, wave = tid >> 6;
    int wm = wave >> 2, wn = wave & 3;
    int lr = lane & 15, lg = lane >> 4;

    f32x4 acc[8][4] = {};

    auto stageA = [&](int db, int sub, int kt) {
#pragma unroll
        for (int l = 0; l < 2; ++l) {
            int chunk = l * 512 + tid;
            int r = chunk >> 3, c16 = chunk & 7;
            int rg = m0 + ((r >> 6) << 7) + (sub << 6) + (r & 63);
            lds_load16(A + (size_t)rg * K + (kt << 6) + ((c16 ^ (r & 7)) << 3),
                       &lds[db][0][sub][chunk * 8]);
        }
    };
    auto stageB = [&](int db, int sub, int kt) {
#pragma unroll
        for (int l = 0; l < 2; ++l) {
            int chunk = l * 512 + tid;
            int r = chunk >> 3, c16 = chunk & 7;
            int rg = n0 + ((r >> 5) << 6) + (sub << 5) + (r & 31);
            lds_load16(Bt + (size_t)rg * K + (kt << 6) + ((c16 ^ (r & 7)) << 3),
                       &lds[db][1][sub][chunk * 8]);
        }
    };
    auto rdA = [&](int db, int sub, int q, int kk) -> bf16x8 {
        int r = (wm << 6) + (q << 4) + lr;
        int cb = ((kk << 6) + (lg << 4)) ^ ((r & 7) << 4);
        return *(const bf16x8*)((const char*)&lds[db][0][sub][0] + r * 128 + cb);
    };
    auto rdB = [&](int db, int j, int kk) -> bf16x8 {
        int sub = j >> 1;
        int r = (wn << 5) + ((j & 1) << 4) + lr;
        int cb = ((kk << 6) + (lg << 4)) ^ ((r & 7) << 4);
        return *(const bf16x8*)((const char*)&lds[db][1][sub][0] + r * 128 + cb);
    };

    stageA(0, 0, 0); stageB(0, 0, 0); stageB(0, 1, 0); stageA(0, 1, 0);
    asm volatile("s_waitcnt vmcnt(4)" ::: "memory");
    __builtin_amdgcn_s_barrier();

    bf16x8 a[4][2], bA[2][2], bB[2][2];
    for (int t = 0; t < NT; ++t) {
        int db = t & 1, dn = db ^ 1;
        bool pf = (t + 1 < NT);
        // ---------- phase 0 ----------
#pragma unroll
        for (int q = 0; q < 4; ++q) { a[q][0] = rdA(db, 0, q, 0); a[q][1] = rdA(db, 0, q, 1); }
#pragma unroll
        for (int j = 0; j < 2; ++j) { bA[j][0] = rdB(db, j, 0); bA[j][1] = rdB(db, j, 1); }
        if (pf) stageA(dn, 0, t + 1);
        __builtin_amdgcn_s_barrier();
        asm volatile("s_waitcnt lgkmcnt(0)" ::: "memory");
        __builtin_amdgcn_sched_barrier(0);
        __builtin_amdgcn_s_setprio(1);
#pragma unroll
        for (int q = 0; q < 4; ++q)
#pragma unroll
            for (int j = 0; j < 2; ++j)
#pragma unroll
                for (int kk = 0; kk < 2; ++kk)
                    acc[q][j] = __builtin_amdgcn_mfma_f32_16x16x32_bf16(a[q][kk], bA[j][kk], acc[q][j], 0, 0, 0);
        __builtin_amdgcn_s_setprio(0);
        if (pf) asm volatile("s_waitcnt vmcnt(4)" ::: "memory");
        else    asm volatile("s_waitcnt vmcnt(2)" ::: "memory");
        __builtin_amdgcn_s_barrier();
        // ---------- phase 1 ----------
#pragma unroll
        for (int j = 0; j < 2; ++j) { bB[j][0] = rdB(db, j + 2, 0); bB[j][1] = rdB(db, j + 2, 1); }
        if (pf) stageB(dn, 0, t + 1);
        __builtin_amdgcn_s_barrier();
        asm volatile("s_waitcnt lgkmcnt(0)" ::: "memory");
        __builtin_amdgcn_sched_barrier(0);
        __builtin_amdgcn_s_setprio(1);
#pragma unroll
        for (int q = 0; q < 4; ++q)
#pragma unroll
            for (int j = 0; j < 2; ++j)
#pragma unroll
                for (int kk = 0; kk < 2; ++kk)
                    acc[q][j + 2] = __builtin_amdgcn_mfma_f32_16x16x32_bf16(a[q][kk], bB[j][kk], acc[q][j + 2], 0, 0, 0);
        __builtin_amdgcn_s_setprio(0);
        if (pf) asm volatile("s_waitcnt vmcnt(4)" ::: "memory");
        else    asm volatile("s_waitcnt vmcnt(0)" ::: "memory");
        __builtin_amdgcn_s_barrier();
        // ---------- phase 2 ----------
#pragma unroll
        for (int q = 0; q < 4; ++q) { a[q][0] = rdA(db, 1, q, 0); a[q][1] = rdA(db, 1, q, 1); }
        if (pf) stageB(dn, 1, t + 1);
        __builtin_amdgcn_s_barrier();
        asm volatile("s_waitcnt lgkmcnt(0)" ::: "memory");
        __builtin_amdgcn_sched_barrier(0);
        __builtin_amdgcn_s_setprio(1);
#pragma unroll
        for (int q = 0; q < 4; ++q)
#pragma unroll
            for (int j = 0; j < 2; ++j)
#pragma unroll
                for (int kk = 0; kk < 2; ++kk)
                    acc[q + 4][j + 2] = __builtin_amdgcn_mfma_f32_16x16x32_bf16(a[q][kk], bB[j][kk], acc[q + 4][j + 2], 0, 0, 0);
        __builtin_amdgcn_s_setprio(0);
        __builtin_amdgcn_s_barrier();
        // ---------- phase 3 ----------
        if (pf) stageA(dn, 1, t + 1);
        __builtin_amdgcn_s_setprio(1);
#pragma unroll
        for (int q = 0; q < 4; ++q)
#pragma unroll
            for (int j = 0; j < 2; ++j)
#pragma unroll
                for (int kk = 0; kk < 2; ++kk)
                    acc[q + 4][j] = __builtin_amdgcn_mfma_f32_16x16x32_bf16(a[q][kk], bA[j][kk], acc[q + 4][j], 0, 0, 0);
        __builtin_amdgcn_s_setprio(0);
        if (pf) asm volatile("s_waitcnt vmcnt(4)" ::: "memory");
        __builtin_amdgcn_s_barrier();
    }

    // -------- epilogue --------
    if (mode == 0) {
        int which = n0 >> 11;  // 0:q 1:k 2:v (block-uniform)
        if (which == 2) {
#pragma unroll
            for (int q = 0; q < 8; ++q) {
                int row_t = (wm << 7) + ((q >> 2) << 6) + ((q & 3) << 4) + (lg << 2);
                int row = m0 + row_t;
                int b_ = row >> 11, tt = row & 2047;   // r=0..3 stays within batch (4-aligned)
#pragma unroll
                for (int j = 0; j < 4; ++j) {
                    int c = n0 + (wn << 6) + (j << 4) + lr;
                    int h = (c & 2047) >> 7, d = c & 127;
                    bf16x4 o;
#pragma unroll
                    for (int r = 0; r < 4; ++r) o[r] = (__bf16)acc[q][j][r];
                    *(bf16x4*)(vt + ((size_t)(b_ * 16 + h) * 128 + d) * 2048 + tt) = o;
                }
            }
        } else {
            // fused RoPE (fp32): exchange the d<->d^64 partner through LDS scratch
            __bf16* dst = (which == 0) ? qb : kb;
            float scale = (which == 0) ? 0.08838834764831845f : 1.f;  // 1/sqrt(128) on q
            int rl = (wm << 4) + (lg << 2);
            int colw = (wn << 6);
#pragma unroll
            for (int q = 0; q < 8; ++q) {
                float* scr = (float*)&lds[q & 1][0][0][0];  // alternate 64KiB halves
                int row_t = (wm << 7) + ((q >> 2) << 6) + ((q & 3) << 4) + (lg << 2);
#pragma unroll
                for (int j = 0; j < 4; ++j)
#pragma unroll
                    for (int r = 0; r < 4; ++r)
                        scr[(rl + r) * 260 + colw + (j << 4) + lr] = acc[q][j][r];
                __syncthreads();
#pragma unroll
                for (int j = 0; j < 4; ++j) {
                    int c = n0 + colw + (j << 4) + lr;
                    int h = (c & 2047) >> 7, d = c & 127;
                    int jj = (j << 4) + lr;  // d % 64
#pragma unroll
                    for (int r = 0; r < 4; ++r) {
                        int row = m0 + row_t + r;
                        int b_ = row >> 11, tt = row & 2047;
                        float2 cs = sc[tt * 64 + jj];
                        float v0 = acc[q][j][r];
                        float v1 = scr[(rl + r) * 260 + (colw ^ 64) + (j << 4) + lr];
                        float o = ((wn & 1) == 0) ? (v0 * cs.x - v1 * cs.y)
                                                  : (v0 * cs.x + v1 * cs.y);
                        dst[((size_t)(b_ * 16 + h) * 2048 + tt) * 128 + d] = (__bf16)(o * scale);
                    }
                }
            }
        }
    } else {
#pragma unroll
        for (int q = 0; q < 8; ++q) {
            int row_t = (wm << 7) + ((q >> 2) << 6) + ((q & 3) << 4) + (lg << 2);
#pragma unroll
            for (int j = 0; j < 4; ++j) {
                int col = n0 + (wn << 6) + (j << 4) + lr;
                float bv = bias[col];
#pragma unroll
                for (int r = 0; r < 4; ++r) {
                    int row = m0 + row_t + r;
                    outp[(size_t)row * 2048 + col] = acc[q][j][r] + bv;
                }
            }
        }
    }
}

// ---------------- causal flash attention, QBLK=128, 8 waves (round-8/12 version) -------
__global__ __launch_bounds__(512, 2) void attn_k(const __bf16* __restrict__ qb,
                                                 const __bf16* __restrict__ kb,
                                                 const __bf16* __restrict__ vt,
                                                 __bf16* __restrict__ ao) {
    __shared__ __bf16 Ks[64 * 128];   // [kv][d], rows 256B, XOR-swizzled
    __shared__ __bf16 Vs[128 * 64];   // [d][kv], rows 128B, XOR-swizzled
    __shared__ __bf16 Ps[8][16 * 64]; // per-wave P^T as [q][kv], rows 128B, swizzled

    int bid = blockIdx.x;
    int qt = 15 - (bid >> 6);
    int bh = bid & 63;
    int qs = qt * 128;
    int tid = threadIdx.x, wave = tid >> 6, lane = tid & 63;
    int lr = lane & 15, lg = lane >> 4;

    bf16x8 qf[4];
    const __bf16* Qrow = qb + ((size_t)bh * 2048 + qs + wave * 16 + lr) * 128;
#pragma unroll
    for (int kk = 0; kk < 4; ++kk) qf[kk] = *(const bf16x8*)(Qrow + kk * 32 + lg * 8);

    f32x4 ot[8] = {};
    float m_run = -1e30f, l_run = 0.f;
    int qmax = qs + wave * 16 + 15;
    int kend = qs + 64;

    for (int ks = 0; ks <= kend; ks += 64) {
#pragma unroll
        for (int i = 0; i < 2; ++i) {
            int c = tid + i * 512;
            {
                int row = c >> 4;
                int cc = c ^ (row & 7);
                int dd = (cc & 15) * 8;
                lds_load16(kb + ((size_t)bh * 2048 + ks + row) * 128 + dd, Ks + c * 8);
            }
            {
                int row = c >> 3;
                int cc = c ^ (row & 7);
                int tt = (cc & 7) * 8;
                lds_load16(vt + ((size_t)bh * 128 + row) * 2048 + ks + tt, Vs + c * 8);
            }
        }
        __syncthreads();

        if (ks <= qmax) {
            f32x4 st[4];
            __builtin_amdgcn_s_setprio(1);
#pragma unroll
            for (int mt = 0; mt < 4; ++mt) {
                f32x4 s = {};
#pragma unroll
                for (int kk = 0; kk < 4; ++kk) {
                    int row = mt * 16 + lr;
                    const __bf16* kp = Ks + row * 128 + ((((kk * 64 + lg * 16)) ^ ((row & 7) << 4)) >> 1);
                    bf16x8 afr = *(const bf16x8*)kp;
                    s = __builtin_amdgcn_mfma_f32_16x16x32_bf16(afr, qf[kk], s, 0, 0, 0);
                }
                st[mt] = s;
            }
            __builtin_amdgcn_s_setprio(0);

            if (ks + 63 > qs + wave * 16) {
                int q = qs + wave * 16 + lr;
#pragma unroll
                for (int mt = 0; mt < 4; ++mt)
#pragma unroll
                    for (int r = 0; r < 4; ++r) {
                        int kv = ks + mt * 16 + lg * 4 + r;
                        if (kv > q) st[mt][r] = -1e30f;
                    }
            }

            float pm = -1e30f;
#pragma unroll
            for (int mt = 0; mt < 4; ++mt)
#pragma unroll
                for (int r = 0; r < 4; ++r) pm = fmaxf(pm, st[mt][r]);
            pm = fmaxf(pm, __shfl_xor(pm, 16));
            pm = fmaxf(pm, __shfl_xor(pm, 32));
            float nm = fmaxf(m_run, pm);
            float alpha = __expf(m_run - nm);
            float psum = 0.f;
#pragma unroll
            for (int mt = 0; mt < 4; ++mt)
#pragma unroll
                for (int r = 0; r < 4; ++r) {
                    float p = __expf(st[mt][r] - nm);
                    psum += p;
                    st[mt][r] = p;
                }
            psum += __shfl_xor(psum, 16);
            psum += __shfl_xor(psum, 32);
            l_run = l_run * alpha + psum;
            m_run = nm;
#pragma unroll
            for (int t8 = 0; t8 < 8; ++t8) ot[t8] *= alpha;

#pragma unroll
            for (int mt = 0; mt < 4; ++mt) {
                bf16x4 pk;
#pragma unroll
                for (int r = 0; r < 4; ++r) pk[r] = (__bf16)st[mt][r];
                int byteoff = lr * 128 + (((mt * 32 + lg * 8)) ^ ((lr & 7) << 4));
                *(bf16x4*)((char*)&Ps[wave][0] + byteoff) = pk;
            }

            bf16x8 pfr[2];
#pragma unroll
            for (int kk = 0; kk < 2; ++kk) {
                const char* pp = (const char*)&Ps[wave][0] + lr * 128 + (((kk * 64 + lg * 16)) ^ ((lr & 7) << 4));
                pfr[kk] = *(const bf16x8*)pp;
            }
            __builtin_amdgcn_s_setprio(1);
#pragma unroll
            for (int dt = 0; dt < 8; ++dt) {
#pragma unroll
                for (int kk = 0; kk < 2; ++kk) {
                    int row = dt * 16 + lr;
                    const __bf16* vp = Vs + row * 64 + ((((kk * 64 + lg * 16)) ^ ((row & 7) << 4)) >> 1);
                    bf16x8 afr = *(const bf16x8*)vp;
                    ot[dt] = __builtin_amdgcn_mfma_f32_16x16x32_bf16(afr, pfr[kk], ot[dt], 0, 0, 0);
                }
            }
            __builtin_amdgcn_s_setprio(0);
        }
        __syncthreads();
    }

    float inv = 1.f / l_run;
    int b_ = bh >> 4, h = bh & 15;
    size_t rowbase = ((size_t)b_ * 2048 + qs + wave * 16 + lr) * 2048 + h * 128;
#pragma unroll
    for (int dt = 0; dt < 8; ++dt) {
        bf16x4 o;
#pragma unroll
        for (int r = 0; r < 4; ++r) o[r] = (__bf16)(ot[dt][r] * inv);
        *(bf16x4*)(ao + rowbase + dt * 16 + lg * 4) = o;
    }
}

// ---------------- launch ----------------
extern "C" void kernel_launch(void* const* d_in, const int* in_sizes, int n_in,
                              void* d_out, int out_size, void* d_ws, size_t ws_size,
                              hipStream_t stream) {
    const float* x      = (const float*)d_in[0];
    const float* w_qkv  = (const float*)d_in[1];
    const float* w_proj = (const float*)d_in[2];
    const float* b_proj = (const float*)d_in[3];
    float* out = (float*)d_out;
    char* ws = (char*)d_ws;

    __bf16* xb  = (__bf16*)(ws);                 // [8192][2048]        33.55 MB
    __bf16* wqt = (__bf16*)(ws + 33554432);      // [6144][2048]        25.17 MB
    __bf16* wpt = (__bf16*)(ws + 58720256);      // [2048][2048]         8.39 MB
    __bf16* qb  = (__bf16*)(ws + 67108864);      // [64][2048][128]     33.55 MB
    __bf16* kb  = (__bf16*)(ws + 100663296);     // [64][2048][128]     33.55 MB
    __bf16* vt  = (__bf16*)(ws + 134217728);     // [64][128][2048]     33.55 MB
    __bf16* ao  = (__bf16*)(ws + 167772160);     // [8192][2048]        33.55 MB
    float2* sc  = (float2*)(ws + 201326592);     // [2048][64]           1.05 MB

    hipLaunchKernelGGL(cvt_k, dim3(8192), dim3(256), 0, stream, x, xb, 2097152);
    hipLaunchKernelGGL(transp_k, dim3(192, 64), dim3(256), 0, stream, w_qkv, wqt, 2048, 6144);
    hipLaunchKernelGGL(transp_k, dim3(64, 64), dim3(256), 0, stream, w_proj, wpt, 2048, 2048);
    hipLaunchKernelGGL(sincos_k, dim3(512), dim3(256), 0, stream, sc);
    // qkv: M=8192, N=6144 -> 32x24 = 768 tiles; RoPE fused in epilogue
    hipLaunchKernelGGL(gemm8_k, dim3(768), dim3(512), 0, stream,
                       xb, wqt, 24, 0, qb, kb, vt, (float*)nullptr, (const float*)nullptr, sc);
    hipLaunchKernelGGL(attn_k, dim3(1024), dim3(512), 0, stream, qb, kb, vt, ao);
    // proj: M=8192, N=2048 -> 32x8 = 256 tiles
    hipLaunchKernelGGL(gemm8_k, dim3(256), dim3(512), 0, stream,
                       ao, wpt, 8, 1, (__bf16*)nullptr, (__bf16*)nullptr, (__bf16*)nullptr,
                       out, b_proj, (const float2*)nullptr);
}